// Round 1
// baseline (355.420 us; speedup 1.0000x reference)
//
#include <hip/hip_runtime.h>

// ALIF 2D layer forward: x [B,T,H,W,C] f32 -> spikes [B,T,H,W,C] f32.
// Recurrence is along T, independent per (b,h,w,c) neuron. One thread
// handles 4 consecutive-C neurons (float4 vectorized), loops over T.
// Memory-bound: 210 MB in + 210 MB out -> ~67 us floor at 6.3 TB/s.

constexpr int B_  = 8;
constexpr int T_  = 50;
constexpr int HWC = 64 * 64 * 32;   // 131072, contiguous per (b,t)
constexpr int NV  = HWC / 4;        // 32768 float4 per (b,t) slab

__global__ __launch_bounds__(256) void alif_fwd_kernel(
    const float4* __restrict__ x, float4* __restrict__ out,
    const float* __restrict__ pd, const float* __restrict__ padp,
    const float* __restrict__ pbeta)
{
    const int tid = blockIdx.x * blockDim.x + threadIdx.x;  // [0, B_*NV)
    const int b   = tid / NV;
    const int p   = tid % NV;

    // Scalars: uniform broadcast loads, cached.
    const float dcy  = *pd;
    const float adp  = *padp;
    const float beta = *pbeta;

    const float4* xp = x   + (size_t)b * T_ * NV + p;
    float4*       op = out + (size_t)b * T_ * NV + p;

    float v[4]  = {0.f, 0.f, 0.f, 0.f};
    float th[4] = {0.f, 0.f, 0.f, 0.f};
    float ps[4] = {0.f, 0.f, 0.f, 0.f};

    for (int t = 0; t < T_; ++t) {
        float4 xv = xp[(size_t)t * NV];
        float xs[4] = {xv.x, xv.y, xv.z, xv.w};
        float s[4];
        #pragma unroll
        for (int i = 0; i < 4; ++i) {
            // Match numpy rounding exactly: no FMA contraction.
            th[i] = __fadd_rn(__fmul_rn(th[i], adp), __fmul_rn(ps[i], beta));
            v[i]  = __fadd_rn(__fmul_rn(v[i], dcy), xs[i]);
            float vth = __fadd_rn(0.5f, th[i]);
            s[i]  = (__fsub_rn(v[i], vth) > 0.0f) ? 1.0f : 0.0f;
            v[i]  = __fsub_rn(v[i], __fmul_rn(s[i], vth));  // soft reset
            ps[i] = s[i];
        }
        float4 ov;
        ov.x = s[0]; ov.y = s[1]; ov.z = s[2]; ov.w = s[3];
        op[(size_t)t * NV] = ov;
    }
}

extern "C" void kernel_launch(void* const* d_in, const int* in_sizes, int n_in,
                              void* d_out, int out_size, void* d_ws, size_t ws_size,
                              hipStream_t stream) {
    const float4* x    = (const float4*)d_in[0];
    const float*  pd   = (const float*)d_in[1];   // hp_alif_d
    const float*  padp = (const float*)d_in[2];   // hp_alif_adp
    const float*  pbet = (const float*)d_in[3];   // hp_alif_beta
    // d_in[4] = hp_alpha: surrogate-grad sharpness, unused in forward.
    float4* out = (float4*)d_out;

    const int total_threads = B_ * NV;            // 262144
    const int block = 256;
    const int grid  = total_threads / block;      // 1024

    alif_fwd_kernel<<<grid, block, 0, stream>>>(x, out, pd, padp, pbet);
}

// Round 3
// 339.814 us; speedup vs baseline: 1.0459x; 1.0459x over previous
//
#include <hip/hip_runtime.h>

// ALIF 2D layer forward: x [B,T,H,W,C] f32 -> spikes [B,T,H,W,C] f32.
// Recurrence along T, independent per neuron. One thread = 4 consecutive-C
// neurons (clang vec4). T-loop software-pipelined in K=5 batches with explicit
// double buffering so 5 loads are in flight while computing the previous 5
// (round 1 was latency-bound: 1 load in flight -> 355 us vs 67 us floor).
// Loads/stores nontemporal: each byte touched exactly once, don't thrash L2.
// NOTE: __builtin_nontemporal_* requires a clang vector type, not HIP float4.

typedef float v4f __attribute__((ext_vector_type(4)));

constexpr int B_  = 8;
constexpr int T_  = 50;
constexpr int HWC = 64 * 64 * 32;   // 131072, contiguous per (b,t)
constexpr int NV  = HWC / 4;        // 32768 vec4 per (b,t) slab
constexpr int K_  = 5;              // timestep batch (divides T=50)

__global__ __launch_bounds__(256) void alif_fwd_kernel(
    const v4f* __restrict__ x, v4f* __restrict__ out,
    const float* __restrict__ pd, const float* __restrict__ padp,
    const float* __restrict__ pbeta)
{
    const int tid = blockIdx.x * blockDim.x + threadIdx.x;  // [0, B_*NV)
    const int b   = tid / NV;
    const int p   = tid % NV;

    const float dcy  = *pd;
    const float adp  = *padp;
    const float beta = *pbeta;

    const v4f* xp = x   + (size_t)b * T_ * NV + p;
    v4f*       op = out + (size_t)b * T_ * NV + p;

    float v[4]  = {0.f, 0.f, 0.f, 0.f};
    float th[4] = {0.f, 0.f, 0.f, 0.f};
    float ps[4] = {0.f, 0.f, 0.f, 0.f};

    // Prime the pipeline: batch 0 in flight.
    v4f cur[K_];
    #pragma unroll
    for (int k = 0; k < K_; ++k)
        cur[k] = __builtin_nontemporal_load(xp + (size_t)k * NV);

    for (int t0 = 0; t0 < T_; t0 += K_) {
        // Issue next batch's loads BEFORE consuming the current batch.
        v4f nxt[K_];
        if (t0 + K_ < T_) {
            #pragma unroll
            for (int k = 0; k < K_; ++k)
                nxt[k] = __builtin_nontemporal_load(xp + (size_t)(t0 + K_ + k) * NV);
        }

        #pragma unroll
        for (int k = 0; k < K_; ++k) {
            float s[4];
            #pragma unroll
            for (int i = 0; i < 4; ++i) {
                const float xi = cur[k][i];
                // Match numpy rounding exactly: no FMA contraction.
                th[i] = __fadd_rn(__fmul_rn(th[i], adp), __fmul_rn(ps[i], beta));
                v[i]  = __fadd_rn(__fmul_rn(v[i], dcy), xi);
                float vth = __fadd_rn(0.5f, th[i]);
                s[i]  = (__fsub_rn(v[i], vth) > 0.0f) ? 1.0f : 0.0f;
                v[i]  = __fsub_rn(v[i], __fmul_rn(s[i], vth));  // soft reset
                ps[i] = s[i];
            }
            v4f ov = {s[0], s[1], s[2], s[3]};
            __builtin_nontemporal_store(ov, op + (size_t)(t0 + k) * NV);
        }

        #pragma unroll
        for (int k = 0; k < K_; ++k) cur[k] = nxt[k];
    }
}

extern "C" void kernel_launch(void* const* d_in, const int* in_sizes, int n_in,
                              void* d_out, int out_size, void* d_ws, size_t ws_size,
                              hipStream_t stream) {
    const v4f*   x    = (const v4f*)d_in[0];
    const float* pd   = (const float*)d_in[1];   // hp_alif_d
    const float* padp = (const float*)d_in[2];   // hp_alif_adp
    const float* pbet = (const float*)d_in[3];   // hp_alif_beta
    // d_in[4] = hp_alpha: surrogate-grad sharpness, unused in forward.
    v4f* out = (v4f*)d_out;

    const int total_threads = B_ * NV;            // 262144
    const int block = 256;
    const int grid  = total_threads / block;      // 1024

    alif_fwd_kernel<<<grid, block, 0, stream>>>(x, out, pd, padp, pbet);
}

// Round 4
// 338.804 us; speedup vs baseline: 1.0490x; 1.0030x over previous
//
#include <hip/hip_runtime.h>

// ALIF 2D layer forward: x [B,T,H,W,C] f32 -> spikes [B,T,H,W,C] f32.
// Recurrence along T, independent per neuron. One thread = 4 consecutive-C
// neurons (clang vec4). T-loop software-pipelined in K=10 batches with
// explicit double buffering: 10 nontemporal loads in flight per wave while
// computing the previous 10 (16 waves/CU -> ~160 KB/CU in flight, >> the
// ~9 KB Little's-law requirement at 900 cy HBM latency / 10 B/cy/CU).
// Traffic floor 420 MB (210 in + 210 out, single-touch -> nt): ~76-84 us
// at realistic mixed read/write HBM rates. Bench dur_us carries ~230-260 us
// of harness restore/poison overhead (kernel absent from rocprof top-5
// whose slowest row is 127 us => kernel dispatch itself is < 127 us).

typedef float v4f __attribute__((ext_vector_type(4)));

constexpr int B_  = 8;
constexpr int T_  = 50;
constexpr int HWC = 64 * 64 * 32;   // 131072, contiguous per (b,t)
constexpr int NV  = HWC / 4;        // 32768 vec4 per (b,t) slab
constexpr int K_  = 10;             // timestep batch (divides T=50)

__global__ __launch_bounds__(256) void alif_fwd_kernel(
    const v4f* __restrict__ x, v4f* __restrict__ out,
    const float* __restrict__ pd, const float* __restrict__ padp,
    const float* __restrict__ pbeta)
{
    const int tid = blockIdx.x * blockDim.x + threadIdx.x;  // [0, B_*NV)
    const int b   = tid / NV;
    const int p   = tid % NV;

    const float dcy  = *pd;
    const float adp  = *padp;
    const float beta = *pbeta;

    const v4f* xp = x   + (size_t)b * T_ * NV + p;
    v4f*       op = out + (size_t)b * T_ * NV + p;

    float v[4]  = {0.f, 0.f, 0.f, 0.f};
    float th[4] = {0.f, 0.f, 0.f, 0.f};
    float ps[4] = {0.f, 0.f, 0.f, 0.f};

    // Prime the pipeline: batch 0 in flight.
    v4f cur[K_];
    #pragma unroll
    for (int k = 0; k < K_; ++k)
        cur[k] = __builtin_nontemporal_load(xp + (size_t)k * NV);

    for (int t0 = 0; t0 < T_; t0 += K_) {
        // Issue next batch's loads BEFORE consuming the current batch.
        v4f nxt[K_];
        if (t0 + K_ < T_) {
            #pragma unroll
            for (int k = 0; k < K_; ++k)
                nxt[k] = __builtin_nontemporal_load(xp + (size_t)(t0 + K_ + k) * NV);
        }

        #pragma unroll
        for (int k = 0; k < K_; ++k) {
            float s[4];
            #pragma unroll
            for (int i = 0; i < 4; ++i) {
                const float xi = cur[k][i];
                // Match numpy rounding exactly: no FMA contraction.
                th[i] = __fadd_rn(__fmul_rn(th[i], adp), __fmul_rn(ps[i], beta));
                v[i]  = __fadd_rn(__fmul_rn(v[i], dcy), xi);
                float vth = __fadd_rn(0.5f, th[i]);
                s[i]  = (__fsub_rn(v[i], vth) > 0.0f) ? 1.0f : 0.0f;
                v[i]  = __fsub_rn(v[i], __fmul_rn(s[i], vth));  // soft reset
                ps[i] = s[i];
            }
            v4f ov = {s[0], s[1], s[2], s[3]};
            __builtin_nontemporal_store(ov, op + (size_t)(t0 + k) * NV);
        }

        #pragma unroll
        for (int k = 0; k < K_; ++k) cur[k] = nxt[k];
    }
}

extern "C" void kernel_launch(void* const* d_in, const int* in_sizes, int n_in,
                              void* d_out, int out_size, void* d_ws, size_t ws_size,
                              hipStream_t stream) {
    const v4f*   x    = (const v4f*)d_in[0];
    const float* pd   = (const float*)d_in[1];   // hp_alif_d
    const float* padp = (const float*)d_in[2];   // hp_alif_adp
    const float* pbet = (const float*)d_in[3];   // hp_alif_beta
    // d_in[4] = hp_alpha: surrogate-grad sharpness, unused in forward.
    v4f* out = (v4f*)d_out;

    const int total_threads = B_ * NV;            // 262144
    const int block = 256;
    const int grid  = total_threads / block;      // 1024

    alif_fwd_kernel<<<grid, block, 0, stream>>>(x, out, pd, padp, pbet);
}